// Round 1
// baseline (1361.175 us; speedup 1.0000x reference)
//
#include <hip/hip_runtime.h>
#include <stdint.h>

#define NN 10000
#define NE 160000
#define DD 512

typedef short bf16x8 __attribute__((ext_vector_type(8)));
typedef float f32x4 __attribute__((ext_vector_type(4)));

typedef __attribute__((address_space(1))) const void gvoid_t;
typedef __attribute__((address_space(3))) void lvoid_t;

__device__ __forceinline__ void gload16(const void* g, void* l) {
    __builtin_amdgcn_global_load_lds((gvoid_t*)g, (lvoid_t*)l, 16, 0, 0);
}

__device__ __forceinline__ unsigned short f2bf(float x) {
    unsigned int u = __float_as_uint(x);
    unsigned int r = (u + 0x7fffu + ((u >> 16) & 1u)) >> 16;
    return (unsigned short)r;
}
__device__ __forceinline__ float bf2f(unsigned short h) {
    return __uint_as_float(((unsigned int)h) << 16);
}

// slot swizzle: involution per row, spreads ds_read_b128 across 8 16B positions
__device__ __forceinline__ int swz(int row, int slot) { return slot ^ ((row >> 1) & 3); }

// ---------------- split fp32 -> bf16 hi/lo ----------------
__global__ void split_kernel(const float* __restrict__ src, unsigned short* __restrict__ hi,
                             unsigned short* __restrict__ lo, int n) {
    int i = blockIdx.x * blockDim.x + threadIdx.x;
    if (i < n) {
        float x = src[i];
        unsigned short h = f2bf(x);
        hi[i] = h;
        lo[i] = f2bf(x - bf2f(h));
    }
}

// ---------------- nfeat passthrough copy ----------------
__global__ void copy_kernel(const float4* __restrict__ s, float4* __restrict__ d, int n4) {
    int i = blockIdx.x * blockDim.x + threadIdx.x;
    if (i < n4) d[i] = s[i];
}

// ---------------- GEMM: C[m,n] = sum_k A[m,k] * W[n,k]  (A fp32, W pre-split bf16) ----------------
// EPI 0: C = acc (f32, ldc)            [node projection -> P]
// EPI 1: h = silu(acc + P[src][n] + P[dst][512+n] + b1[n])   -> Cout [M][512] f32
// EPI 2: C = acc + b2[n]               [y -> d_out]
template <int EPI>
__global__ __launch_bounds__(256, 2) void gemm_kernel(
    const float* __restrict__ A, const unsigned short* __restrict__ Bh,
    const unsigned short* __restrict__ Bl, float* __restrict__ Cout, int M, int ldc,
    const int* __restrict__ srcI, const int* __restrict__ dstI, const float* __restrict__ P,
    const float* __restrict__ bias) {
    __shared__ unsigned short AhS[4096], AlS[4096], BhS[4096], BlS[4096];  // 128x32 each, 32KB

    const int tid = threadIdx.x;
    const int lane = tid & 63;
    const int wid = tid >> 6;
    const int wr = wid >> 1, wc = wid & 1;  // 2x2 wave grid, each wave 64x64
    const int m0 = blockIdx.y * 128, n0 = blockIdx.x * 128;

    f32x4 acc[4][4];
#pragma unroll
    for (int i = 0; i < 4; i++)
#pragma unroll
        for (int j = 0; j < 4; j++)
#pragma unroll
            for (int e = 0; e < 4; e++) acc[i][j][e] = 0.f;

    // A staging assignment: thread covers row=tid>>1, 16 cols starting kh*16
    const int arow = tid >> 1;
    const int akh = tid & 1;
    const int sRow = min(m0 + arow, M - 1);  // clamp for partial M tiles (reads-only; stores guarded)
    const float* Aptr = A + (size_t)sRow * DD + akh * 16;
    const int axr = (arow >> 1) & 3;  // swizzle key for this row

    for (int kt = 0; kt < 16; ++kt) {
        const int k0 = kt * 32;
        // ---- stage B hi/lo via global_load_lds (linear LDS dest, pre-swizzled global src)
#pragma unroll
        for (int is = 0; is < 2; ++is) {
            int flat = is * 256 + tid;
            int brow = flat >> 2, bslot = flat & 3;
            int gs = swz(brow, bslot);
            size_t gb = (size_t)(n0 + brow) * DD + k0 + gs * 8;
            gload16(Bh + gb, (char*)BhS + flat * 16);
            gload16(Bl + gb, (char*)BlS + flat * 16);
        }
        // ---- stage A: load fp32, split to bf16 hi/lo, swizzled ds_write
        {
            const float* ap = Aptr + k0;
#pragma unroll
            for (int g = 0; g < 4; ++g) {
                float4 v = *(const float4*)(ap + g * 4);
                float xv[4] = {v.x, v.y, v.z, v.w};
                unsigned short h[4], l[4];
#pragma unroll
                for (int j = 0; j < 4; j++) {
                    h[j] = f2bf(xv[j]);
                    l[j] = f2bf(xv[j] - bf2f(h[j]));
                }
                uint2 hw, lw;
                hw.x = (unsigned int)h[0] | ((unsigned int)h[1] << 16);
                hw.y = (unsigned int)h[2] | ((unsigned int)h[3] << 16);
                lw.x = (unsigned int)l[0] | ((unsigned int)l[1] << 16);
                lw.y = (unsigned int)l[2] | ((unsigned int)l[3] << 16);
                int slot = 2 * akh + (g >> 1);
                int sp = slot ^ axr;
                int boff = arow * 64 + sp * 16 + (g & 1) * 8;
                *(uint2*)((char*)AhS + boff) = hw;
                *(uint2*)((char*)AlS + boff) = lw;
            }
        }
        __syncthreads();

        // ---- fragments + MFMA (hi*hi + hi*lo + lo*hi)
        const int r16 = lane & 15, ko = lane >> 4;
        bf16x8 ah[4], al[4], bh[4], bl[4];
#pragma unroll
        for (int mi = 0; mi < 4; ++mi) {
            int row = wr * 64 + mi * 16 + r16;
            int off = row * 64 + swz(row, ko) * 16;
            ah[mi] = *(const bf16x8*)((const char*)AhS + off);
            al[mi] = *(const bf16x8*)((const char*)AlS + off);
        }
#pragma unroll
        for (int ni = 0; ni < 4; ++ni) {
            int row = wc * 64 + ni * 16 + r16;
            int off = row * 64 + swz(row, ko) * 16;
            bh[ni] = *(const bf16x8*)((const char*)BhS + off);
            bl[ni] = *(const bf16x8*)((const char*)BlS + off);
        }
#pragma unroll
        for (int mi = 0; mi < 4; ++mi)
#pragma unroll
            for (int ni = 0; ni < 4; ++ni) {
                acc[mi][ni] = __builtin_amdgcn_mfma_f32_16x16x32_bf16(ah[mi], bh[ni], acc[mi][ni], 0, 0, 0);
                acc[mi][ni] = __builtin_amdgcn_mfma_f32_16x16x32_bf16(ah[mi], bl[ni], acc[mi][ni], 0, 0, 0);
                acc[mi][ni] = __builtin_amdgcn_mfma_f32_16x16x32_bf16(al[mi], bh[ni], acc[mi][ni], 0, 0, 0);
            }
        __syncthreads();
    }

    // ---- epilogue. C/D layout: col = lane&15, row = (lane>>4)*4 + i   [m89-verified]
    const int r16 = lane & 15, ko = lane >> 4;
    float bcol[4];
    if (EPI != 0) {
#pragma unroll
        for (int ni = 0; ni < 4; ++ni) bcol[ni] = bias[n0 + wc * 64 + ni * 16 + r16];
    }
#pragma unroll
    for (int mi = 0; mi < 4; ++mi) {
#pragma unroll
        for (int i = 0; i < 4; ++i) {
            int r = m0 + wr * 64 + mi * 16 + ko * 4 + i;
            if (EPI == 0) {
                if (r < M) {
#pragma unroll
                    for (int ni = 0; ni < 4; ++ni) {
                        int col = n0 + wc * 64 + ni * 16 + r16;
                        Cout[(size_t)r * ldc + col] = acc[mi][ni][i];
                    }
                }
            } else if (EPI == 1) {
                const float* Ps = P + (size_t)srcI[r] * 1024;
                const float* Pd = P + (size_t)dstI[r] * 1024 + 512;
#pragma unroll
                for (int ni = 0; ni < 4; ++ni) {
                    int col = n0 + wc * 64 + ni * 16 + r16;
                    float v = acc[mi][ni][i] + Ps[col] + Pd[col] + bcol[ni];
                    float sg = __fdividef(1.f, 1.f + __expf(-v));
                    Cout[(size_t)r * DD + col] = v * sg;
                }
            } else {
#pragma unroll
                for (int ni = 0; ni < 4; ++ni) {
                    int col = n0 + wc * 64 + ni * 16 + r16;
                    Cout[(size_t)r * DD + col] = acc[mi][ni][i] + bcol[ni];
                }
            }
        }
    }
}

// ---------------- LayerNorm + residual, in place on d_out ----------------
__global__ __launch_bounds__(256) void ln_residual_kernel(float* __restrict__ y,
                                                          const float* __restrict__ ef,
                                                          const float* __restrict__ gamma,
                                                          const float* __restrict__ beta) {
    const int lane = threadIdx.x & 63;
    const int wv = threadIdx.x >> 6;
    const size_t row = (size_t)blockIdx.x * 4 + wv;  // one wave per row
    float* yr = y + row * DD;
    const int c0 = lane * 8;
    float4 a = *(const float4*)(yr + c0);
    float4 b = *(const float4*)(yr + c0 + 4);
    float s = (a.x + a.y) + (a.z + a.w) + (b.x + b.y) + (b.z + b.w);
    float q = (a.x * a.x + a.y * a.y) + (a.z * a.z + a.w * a.w) +
              (b.x * b.x + b.y * b.y) + (b.z * b.z + b.w * b.w);
#pragma unroll
    for (int m = 32; m > 0; m >>= 1) {
        s += __shfl_xor(s, m);
        q += __shfl_xor(q, m);
    }
    const float mu = s * (1.f / 512.f);
    const float var = q * (1.f / 512.f) - mu * mu;
    const float rs = rsqrtf(var + 1e-5f);
    const float* er = ef + row * DD;
    float4 e0 = *(const float4*)(er + c0);
    float4 e1 = *(const float4*)(er + c0 + 4);
    float4 g0 = *(const float4*)(gamma + c0);
    float4 g1 = *(const float4*)(gamma + c0 + 4);
    float4 t0 = *(const float4*)(beta + c0);
    float4 t1 = *(const float4*)(beta + c0 + 4);
    float4 o0, o1;
    o0.x = (a.x - mu) * rs * g0.x + t0.x + e0.x;
    o0.y = (a.y - mu) * rs * g0.y + t0.y + e0.y;
    o0.z = (a.z - mu) * rs * g0.z + t0.z + e0.z;
    o0.w = (a.w - mu) * rs * g0.w + t0.w + e0.w;
    o1.x = (b.x - mu) * rs * g1.x + t1.x + e1.x;
    o1.y = (b.y - mu) * rs * g1.y + t1.y + e1.y;
    o1.z = (b.z - mu) * rs * g1.z + t1.z + e1.z;
    o1.w = (b.w - mu) * rs * g1.w + t1.w + e1.w;
    *(float4*)(yr + c0) = o0;
    *(float4*)(yr + c0 + 4) = o1;
}

extern "C" void kernel_launch(void* const* d_in, const int* in_sizes, int n_in, void* d_out,
                              int out_size, void* d_ws, size_t ws_size, hipStream_t stream) {
    const float* efeat = (const float*)d_in[0];
    const float* nfeat = (const float*)d_in[1];
    const int* src = (const int*)d_in[2];
    const int* dst = (const int*)d_in[3];
    const float* W_e = (const float*)d_in[4];
    const float* W_s = (const float*)d_in[5];
    const float* W_d = (const float*)d_in[6];
    const float* b1 = (const float*)d_in[7];
    const float* W2 = (const float*)d_in[8];
    const float* b2 = (const float*)d_in[9];
    const float* gamma = (const float*)d_in[10];
    const float* beta = (const float*)d_in[11];
    float* out = (float*)d_out;

    // workspace layout (~373 MB)
    char* ws = (char*)d_ws;
    size_t off = 0;
    unsigned short* Wsd_h = (unsigned short*)(ws + off); off += (size_t)1024 * 512 * 2;
    unsigned short* Wsd_l = (unsigned short*)(ws + off); off += (size_t)1024 * 512 * 2;
    unsigned short* We_h = (unsigned short*)(ws + off);  off += (size_t)512 * 512 * 2;
    unsigned short* We_l = (unsigned short*)(ws + off);  off += (size_t)512 * 512 * 2;
    unsigned short* W2_h = (unsigned short*)(ws + off);  off += (size_t)512 * 512 * 2;
    unsigned short* W2_l = (unsigned short*)(ws + off);  off += (size_t)512 * 512 * 2;
    float* P = (float*)(ws + off); off += (size_t)NN * 1024 * 4;
    float* H = (float*)(ws + off); off += (size_t)NE * DD * 4;

    const int nW = 512 * 512;
    split_kernel<<<(nW + 255) / 256, 256, 0, stream>>>(W_s, Wsd_h, Wsd_l, nW);
    split_kernel<<<(nW + 255) / 256, 256, 0, stream>>>(W_d, Wsd_h + nW, Wsd_l + nW, nW);
    split_kernel<<<(nW + 255) / 256, 256, 0, stream>>>(W_e, We_h, We_l, nW);
    split_kernel<<<(nW + 255) / 256, 256, 0, stream>>>(W2, W2_h, W2_l, nW);

    // P[i][0:512] = nfeat@W_s^T, P[i][512:1024] = nfeat@W_d^T
    gemm_kernel<0><<<dim3(8, 79), 256, 0, stream>>>(nfeat, Wsd_h, Wsd_l, P, NN, 1024,
                                                    nullptr, nullptr, nullptr, nullptr);
    // h = silu(efeat@W_e^T + gather + b1)
    gemm_kernel<1><<<dim3(4, 1250), 256, 0, stream>>>(efeat, We_h, We_l, H, NE, DD,
                                                      src, dst, P, b1);
    // y = h@W2^T + b2  -> d_out
    gemm_kernel<2><<<dim3(4, 1250), 256, 0, stream>>>(H, W2_h, W2_l, out, NE, DD,
                                                      nullptr, nullptr, nullptr, b2);
    // LayerNorm + residual in place
    ln_residual_kernel<<<NE / 4, 256, 0, stream>>>(out, efeat, gamma, beta);
    // nfeat passthrough (second tuple output)
    copy_kernel<<<(NN * DD / 4 + 255) / 256, 256, 0, stream>>>(
        (const float4*)nfeat, (float4*)(out + (size_t)NE * DD), NN * DD / 4);
}